// Round 6
// baseline (360.782 us; speedup 1.0000x reference)
//
#include <hip/hip_runtime.h>
#include <hip/hip_bf16.h>

// out[n] = sum_k U[k] * relu( x1[n,:] . M[k,:] + c[k] )
//   M[k,d] = V[k,d] + sum_e W[k,d,e]*x2[e]        (K=16, D=128)
//   c[k]   = sum_e V[k,128+e]*x2[e] + b[k]
//
// R6 main: every global load is a contiguous 1-KB wave access (lane*16B linear
// over a 16-row x 512B tile), waves own contiguous 64-KB chunks of x1 (DRAM
// stream locality). Fragments built through a wave-private 4-KB LDS buffer:
// f32 regs -> cvt_pk bf16 -> ds_write_b64 -> XOR-swizzled ds_read_b128 in
// MFMA A-fragment order (conflict-free both directions; no __syncthreads —
// same-wave DS ops are in-order). M kept as register-resident split-bf16
// B-fragments (Bh+Bl), 8 MFMA per tile.

#define D 128
#define KK 16

typedef __attribute__((ext_vector_type(8))) short bf16x8;
typedef __attribute__((ext_vector_type(4))) float f32x4;

__device__ __forceinline__ unsigned short f2bf(float f) {   // RNE
    unsigned u = __float_as_uint(f);
    unsigned t = u + 0x7fffu + ((u >> 16) & 1u);
    return (unsigned short)(t >> 16);
}
__device__ __forceinline__ float bf2f(unsigned short s) {
    return __uint_as_float(((unsigned)s) << 16);
}

// ---------- prep: wave per M element (2048) + wave per c element (16) ----------
// Writes Mh/Ml in B-fragment order: b[kb*512 + lane*8 + j] = bf16(M[n][kb*32+kk])
// where lane = n | ((kk>>3)<<4), j = kk&7  (B[k][n]: n=lane&15, k=(lane>>4)*8+j).
__global__ __launch_bounds__(256) void ntn_prep(const float* __restrict__ x2,
                                                const float* __restrict__ V,
                                                const float* __restrict__ W,
                                                const float* __restrict__ b,
                                                unsigned short* __restrict__ bh,
                                                unsigned short* __restrict__ bl,
                                                float* __restrict__ c) {
    const int gtid = blockIdx.x * 256 + threadIdx.x;
    const int wave = gtid >> 6;
    const int lane = gtid & 63;
    if (wave >= KK * D + KK) return;

    float p;
    if (wave < KK * D) {
        const int k = wave >> 7, d = wave & (D - 1);
        const float* Wr = W + ((size_t)(k * D + d)) * D;
        p = Wr[lane] * x2[lane] + Wr[lane + 64] * x2[lane + 64];
    } else {
        const int k = wave - KK * D;
        const float* Vr = V + (size_t)k * 2 * D + D;
        p = Vr[lane] * x2[lane] + Vr[lane + 64] * x2[lane + 64];
    }
#pragma unroll
    for (int m = 32; m; m >>= 1) p += __shfl_xor(p, m);

    if (lane == 0) {
        if (wave < KK * D) {
            const int k = wave >> 7, d = wave & (D - 1);
            float Mv = V[(size_t)k * 2 * D + d] + p;
            unsigned short hb = f2bf(Mv);
            unsigned short lb = f2bf(Mv - bf2f(hb));
            const int kb = d >> 5, kk = d & 31;
            const int fl = k | ((kk >> 3) << 4);
            const int idx = kb * 512 + fl * 8 + (kk & 7);
            bh[idx] = hb;
            bl[idx] = lb;
        } else {
            const int k = wave - KK * D;
            c[k] = p + b[k];
        }
    }
}

__device__ __forceinline__ uint2 pack4(const float4& v) {
    union { __hip_bfloat162 h; unsigned u; } a, b;
    a.h = __float22bfloat162_rn(make_float2(v.x, v.y));
    b.h = __float22bfloat162_rn(make_float2(v.z, v.w));
    uint2 r; r.x = a.u; r.y = b.u; return r;
}

// ---------- main ----------
__global__ __launch_bounds__(256, 4) void ntn_main(const float* __restrict__ x1,
                                                   const unsigned short* __restrict__ bhp,
                                                   const unsigned short* __restrict__ blp,
                                                   const float* __restrict__ cp,
                                                   const float* __restrict__ Up,
                                                   float* __restrict__ out,
                                                   int NT, int C) {
    __shared__ unsigned char lds[4 * 4096];   // 4 KB per wave (16 rows x 128 bf16)

    const int t = threadIdx.x;
    const int l = t & 63;
    const int gw = blockIdx.x * 4 + (t >> 6);
    unsigned char* const L = lds + (t >> 6) * 4096;

    // B fragments (loaded once): 32 VGPR
    bf16x8 Bh[4], Bl[4];
#pragma unroll
    for (int kb = 0; kb < 4; ++kb) {
        Bh[kb] = *(const bf16x8*)(bhp + kb * 512 + l * 8);
        Bl[kb] = *(const bf16x8*)(blp + kb * 512 + l * 8);
    }
    const int m = l & 15;     // A row in tile / C col (k) owner
    const int q = l >> 4;     // A k-quad / C row quad
    const float cl = cp[m];
    const float ul = Up[m];

    const int start = gw * C;
    if (start >= NT) return;
    const int end = (start + C < NT) ? start + C : NT;

    // LDS addresses (lane-fixed):
    //  write (load i): row r = (l>>5)+2i, byte col cb=(l&31)*8, addr = r*256 + (cb ^ ((r&7)*16))
    //  read (frag kb): addr = m*256 + ((kb*64 + q*16) ^ ((m&7)*16))
    const int wr_r0 = (l >> 5);
    const int wr_cb = (l & 31) * 8;
    int rd_off[4];
#pragma unroll
    for (int kb = 0; kb < 4; ++kb)
        rd_off[kb] = m * 256 + ((kb * 64 + q * 16) ^ ((m & 7) * 16));

    const float4* const f4 = (const float4*)x1;

    // ---- prologue: stage tile 'start' ----
    {
        float4 g[8];
        const size_t base = (size_t)start * 512 + l;
#pragma unroll
        for (int i = 0; i < 8; ++i) g[i] = f4[base + i * 64];
#pragma unroll
        for (int i = 0; i < 8; ++i) {
            const int r = wr_r0 + 2 * i;
            *(uint2*)(L + r * 256 + (wr_cb ^ ((r & 7) * 16))) = pack4(g[i]);
        }
    }

    for (int i = start; i < end; ++i) {
        const bool has = (i + 1 < end);
        float4 g2[8];
        if (has) {
            const size_t base = (size_t)(i + 1) * 512 + l;
#pragma unroll
            for (int j = 0; j < 8; ++j) g2[j] = f4[base + j * 64];
        }

        // frags from LDS + MFMA
        f32x4 accA = {0.f, 0.f, 0.f, 0.f};
        f32x4 accB = {0.f, 0.f, 0.f, 0.f};
#pragma unroll
        for (int kb = 0; kb < 4; ++kb) {
            bf16x8 ah = *(const bf16x8*)(L + rd_off[kb]);
            accA = __builtin_amdgcn_mfma_f32_16x16x32_bf16(ah, Bh[kb], accA, 0, 0, 0);
            accB = __builtin_amdgcn_mfma_f32_16x16x32_bf16(ah, Bl[kb], accB, 0, 0, 0);
        }

        // epilogue: relu + U, reduce over k (lanes m), float4 store
        {
            float vv[4];
#pragma unroll
            for (int r = 0; r < 4; ++r) {
                float s = accA[r] + accB[r] + cl;
                vv[r] = ul * fmaxf(s, 0.f);
                vv[r] += __shfl_xor(vv[r], 1);
                vv[r] += __shfl_xor(vv[r], 2);
                vv[r] += __shfl_xor(vv[r], 4);
                vv[r] += __shfl_xor(vv[r], 8);
            }
            if (m == 0)
                *(float4*)(out + (size_t)i * 16 + q * 4) =
                    make_float4(vv[0], vv[1], vv[2], vv[3]);
        }

        // stage next tile (same-wave DS ordering keeps this after the reads)
        if (has) {
#pragma unroll
            for (int j = 0; j < 8; ++j) {
                const int r = wr_r0 + 2 * j;
                *(uint2*)(L + r * 256 + (wr_cb ^ ((r & 7) * 16))) = pack4(g2[j]);
            }
        }
    }
}

extern "C" void kernel_launch(void* const* d_in, const int* in_sizes, int n_in,
                              void* d_out, int out_size, void* d_ws, size_t ws_size,
                              hipStream_t stream) {
    const float* x1 = (const float*)d_in[0];
    const float* x2 = (const float*)d_in[1];
    const float* V  = (const float*)d_in[2];
    const float* W  = (const float*)d_in[3];
    const float* b  = (const float*)d_in[4];
    const float* U  = (const float*)d_in[5];
    float* out = (float*)d_out;

    unsigned short* bh = (unsigned short*)d_ws;          // 2048 bf16
    unsigned short* bl = bh + KK * D;                    // 2048 bf16
    float* c = (float*)(bl + KK * D);                    // 16 f32

    const int N = in_sizes[0] / D;    // 500000
    const int NT = N >> 4;            // 31250 tiles of 16 rows (exact)

    ntn_prep<<<516, 256, 0, stream>>>(x2, V, W, b, bh, bl, c);

    // 1024 blocks x 4 waves = 4096 waves; each owns a contiguous chunk of
    // C = ceil(NT/4096) = 8 tiles (64 KB of x1).
    const int waves = 1024 * 4;
    const int C = (NT + waves - 1) / waves;
    ntn_main<<<1024, 256, 0, stream>>>(x1, bh, bl, c, U, out, NT, C);
}

// Round 8
// 326.269 us; speedup vs baseline: 1.1058x; 1.1058x over previous
//
#include <hip/hip_runtime.h>
#include <hip/hip_bf16.h>

// out[n] = sum_k U[k] * relu( x1[n,:] . M[k,:] + c[k] )
//   M[k,d] = V[k,d] + sum_e W[k,d,e]*x2[e]        (K=16, D=128)
//   c[k]   = sum_e V[k,128+e]*x2[e] + b[k]
//
// R8 = R7 with the nontemporal builtin applied to clang native vectors
// (HIP_vector_type float4* is rejected by __builtin_nontemporal_*).
// Structure: ONE WAVE PER 16-ROW TILE (31250 independent waves), tid-linear
// 1-KB wave loads sweeping x1 front-to-back, x1 loads NON-TEMPORAL (read-once;
// avoid L3 allocation -> avoid dirty-line writebacks from the harness's 1GB
// ws-poison + x1-restore). Fragments via verified per-wave LDS XOR-swizzle
// round-trip. M register-resident as split-bf16 B-fragments, 8 MFMA/tile.

#define D 128
#define KK 16

typedef __attribute__((ext_vector_type(8))) short bf16x8;
typedef __attribute__((ext_vector_type(4))) float f32x4;     // MFMA acc
typedef __attribute__((ext_vector_type(4))) float f32x4v;    // native vec for nt ld/st

__device__ __forceinline__ unsigned short f2bf(float f) {   // RNE
    unsigned u = __float_as_uint(f);
    unsigned t = u + 0x7fffu + ((u >> 16) & 1u);
    return (unsigned short)(t >> 16);
}
__device__ __forceinline__ float bf2f(unsigned short s) {
    return __uint_as_float(((unsigned)s) << 16);
}

// ---------- prep: wave per M element (2048) + wave per c element (16) ----------
// Writes Mh/Ml in B-fragment order: b[kb*512 + lane*8 + j] = bf16(M[n][kb*32+kk])
// where lane = n | ((kk>>3)<<4), j = kk&7  (B[k][n]: n=lane&15, k=(lane>>4)*8+j).
__global__ __launch_bounds__(256) void ntn_prep(const float* __restrict__ x2,
                                                const float* __restrict__ V,
                                                const float* __restrict__ W,
                                                const float* __restrict__ b,
                                                unsigned short* __restrict__ bh,
                                                unsigned short* __restrict__ bl,
                                                float* __restrict__ c) {
    const int gtid = blockIdx.x * 256 + threadIdx.x;
    const int wave = gtid >> 6;
    const int lane = gtid & 63;
    if (wave >= KK * D + KK) return;

    float p;
    if (wave < KK * D) {
        const int k = wave >> 7, d = wave & (D - 1);
        const float* Wr = W + ((size_t)(k * D + d)) * D;
        p = Wr[lane] * x2[lane] + Wr[lane + 64] * x2[lane + 64];
    } else {
        const int k = wave - KK * D;
        const float* Vr = V + (size_t)k * 2 * D + D;
        p = Vr[lane] * x2[lane] + Vr[lane + 64] * x2[lane + 64];
    }
#pragma unroll
    for (int m = 32; m; m >>= 1) p += __shfl_xor(p, m);

    if (lane == 0) {
        if (wave < KK * D) {
            const int k = wave >> 7, d = wave & (D - 1);
            float Mv = V[(size_t)k * 2 * D + d] + p;
            unsigned short hb = f2bf(Mv);
            unsigned short lb = f2bf(Mv - bf2f(hb));
            const int kb = d >> 5, kk = d & 31;
            const int fl = k | ((kk >> 3) << 4);
            const int idx = kb * 512 + fl * 8 + (kk & 7);
            bh[idx] = hb;
            bl[idx] = lb;
        } else {
            const int k = wave - KK * D;
            c[k] = p + b[k];
        }
    }
}

__device__ __forceinline__ uint2 pack4(const f32x4v& v) {
    union { __hip_bfloat162 h; unsigned u; } a, b;
    a.h = __float22bfloat162_rn(make_float2(v.x, v.y));
    b.h = __float22bfloat162_rn(make_float2(v.z, v.w));
    uint2 r; r.x = a.u; r.y = b.u; return r;
}

// ---------- main: one wave per 16-row tile ----------
__global__ __launch_bounds__(256) void ntn_main(const float* __restrict__ x1,
                                                const unsigned short* __restrict__ bhp,
                                                const unsigned short* __restrict__ blp,
                                                const float* __restrict__ cp,
                                                const float* __restrict__ Up,
                                                float* __restrict__ out,
                                                int NT) {
    __shared__ unsigned char lds[4 * 4096];   // 4 KB per wave (16 rows x 128 bf16)

    const int t = threadIdx.x;
    const int l = t & 63;
    const int wid = t >> 6;
    const int tile = blockIdx.x * 4 + wid;
    unsigned char* const L = lds + wid * 4096;

    // B fragments (loaded once): 32 VGPR
    bf16x8 Bh[4], Bl[4];
#pragma unroll
    for (int kb = 0; kb < 4; ++kb) {
        Bh[kb] = *(const bf16x8*)(bhp + kb * 512 + l * 8);
        Bl[kb] = *(const bf16x8*)(blp + kb * 512 + l * 8);
    }
    const int m = l & 15;     // A row in tile / C col (k) owner
    const int q = l >> 4;     // A k-quad / C row quad
    const float cl = cp[m];
    const float ul = Up[m];

    if (tile >= NT) return;

    // ---- load my 8-KB tile: 8 x 1-KB contiguous wave loads, NON-TEMPORAL ----
    f32x4v g[8];
    {
        const f32x4v* const f4 = (const f32x4v*)x1 + (size_t)tile * 512 + l;
#pragma unroll
        for (int j = 0; j < 8; ++j)
            g[j] = __builtin_nontemporal_load(f4 + j * 64);
    }

    // ---- cvt + LDS redistribute (verified XOR-16B swizzle; same-wave DS order) ----
    //  write (load j): row r = (l>>5)+2j, byte col cb=(l&31)*8, addr = r*256 + (cb ^ ((r&7)*16))
    {
        const int wr_r0 = (l >> 5);
        const int wr_cb = (l & 31) * 8;
#pragma unroll
        for (int j = 0; j < 8; ++j) {
            const int r = wr_r0 + 2 * j;
            *(uint2*)(L + r * 256 + (wr_cb ^ ((r & 7) * 16))) = pack4(g[j]);
        }
    }

    // ---- fragments + MFMA ----
    f32x4 accA = {0.f, 0.f, 0.f, 0.f};
    f32x4 accB = {0.f, 0.f, 0.f, 0.f};
#pragma unroll
    for (int kb = 0; kb < 4; ++kb) {
        const int rd = m * 256 + ((kb * 64 + q * 16) ^ ((m & 7) * 16));
        bf16x8 ah = *(const bf16x8*)(L + rd);
        accA = __builtin_amdgcn_mfma_f32_16x16x32_bf16(ah, Bh[kb], accA, 0, 0, 0);
        accB = __builtin_amdgcn_mfma_f32_16x16x32_bf16(ah, Bl[kb], accB, 0, 0, 0);
    }

    // ---- epilogue: relu + U, reduce over k (lanes m), float4 nt store ----
    float vv[4];
#pragma unroll
    for (int r = 0; r < 4; ++r) {
        float s = accA[r] + accB[r] + cl;
        vv[r] = ul * fmaxf(s, 0.f);
        vv[r] += __shfl_xor(vv[r], 1);
        vv[r] += __shfl_xor(vv[r], 2);
        vv[r] += __shfl_xor(vv[r], 4);
        vv[r] += __shfl_xor(vv[r], 8);
    }
    if (m == 0) {
        f32x4v v = {vv[0], vv[1], vv[2], vv[3]};
        __builtin_nontemporal_store(v, (f32x4v*)(out + (size_t)tile * 16 + q * 4));
    }
}

extern "C" void kernel_launch(void* const* d_in, const int* in_sizes, int n_in,
                              void* d_out, int out_size, void* d_ws, size_t ws_size,
                              hipStream_t stream) {
    const float* x1 = (const float*)d_in[0];
    const float* x2 = (const float*)d_in[1];
    const float* V  = (const float*)d_in[2];
    const float* W  = (const float*)d_in[3];
    const float* b  = (const float*)d_in[4];
    const float* U  = (const float*)d_in[5];
    float* out = (float*)d_out;

    unsigned short* bh = (unsigned short*)d_ws;          // 2048 bf16
    unsigned short* bl = bh + KK * D;                    // 2048 bf16
    float* c = (float*)(bl + KK * D);                    // 16 f32

    const int N = in_sizes[0] / D;    // 500000
    const int NT = N >> 4;            // 31250 tiles of 16 rows (exact)

    ntn_prep<<<516, 256, 0, stream>>>(x2, V, W, b, bh, bl, c);

    // one wave per tile: 31250 waves -> 7813 blocks x 4 waves
    const int blocks = (NT + 3) / 4;
    ntn_main<<<blocks, 256, 0, stream>>>(x1, bh, bl, c, U, out, NT);
}